// Round 1
// baseline (238.678 us; speedup 1.0000x reference)
//
#include <hip/hip_runtime.h>

#define NGRAPHS 256
#define DIM     256
#define HID     128
#define TILE    128   // rows per block in k_scores
#define KT      32    // k-tile depth

// ---------------------------------------------------------------------------
// Kernel 1: per 128-row tile:
//   scores s_i = tanh(x_i @ w1 + b1) @ w2 + b2   (fp32 register-tiled GEMM)
//   e_i = exp(s_i)
//   partial[slot][d] = sum_{i in tile, graph==slot's graph} e_i * x[i][d]
//   esum[block] = sum_i e_i
// Deterministic: fixed partition, no atomics.
// ---------------------------------------------------------------------------
__global__ __launch_bounds__(256, 3) void k_scores(
    const float* __restrict__ x, const int* __restrict__ batch,
    const float* __restrict__ w1, const float* __restrict__ b1,
    const float* __restrict__ w2, const float* __restrict__ b2,
    float* __restrict__ wsp,   // [nblk][2][256] partial segment sums
    float* __restrict__ wse,   // [nblk] exp-sums
    int*   __restrict__ wsid,  // [nblk] first graph id in tile
    int n)
{
    __shared__ float xT[KT][132];     // transposed x tile, padded (132 % 4 == 0)
    __shared__ float w1t[KT][HID];    // w1 tile, natural layout
    __shared__ float hp[TILE][17];    // per-row partial of tanh(h)@w2, padded
    __shared__ float evals[TILE];
    __shared__ int   gid[TILE];
    __shared__ float ep[4];

    const int t  = threadIdx.x;
    const int b  = blockIdx.x;
    const int r0 = b * TILE;
    const int m8 = (t >> 4) * 8;   // thread-tile row offset (0..120)
    const int n8 = (t & 15) * 8;   // thread-tile col offset (0..120)

    // preload bias / w2 slices (L1/L2 resident)
    float bv[8], wv[8];
#pragma unroll
    for (int j = 0; j < 8; ++j) { bv[j] = b1[n8 + j]; wv[j] = w2[n8 + j]; }

    float acc[8][8];
#pragma unroll
    for (int i = 0; i < 8; ++i)
#pragma unroll
        for (int j = 0; j < 8; ++j) acc[i][j] = 0.f;

    // stage graph ids for this tile
    if (t < TILE) {
        int r = r0 + t;
        gid[t] = batch[r < n ? r : (n - 1)];
    }

    // ---- GEMM: h = x_tile @ w1, k-tiled ----
    for (int kt = 0; kt < DIM / KT; ++kt) {
        // stage w1 k-tile: KT*HID = 4096 floats, linear, coalesced
        {
            const float4* src = (const float4*)(w1 + kt * KT * HID);
            float4* dst = (float4*)(&w1t[0][0]);
#pragma unroll
            for (int i = 0; i < (KT * HID / 4) / 256; ++i)   // = 4
                dst[t + i * 256] = src[t + i * 256];
        }
        // stage x k-tile transposed: 128 rows x 32 k
        {
            const int q  = t & 7;    // k-chunk of 4
            const int rb = t >> 3;   // 0..31
#pragma unroll
            for (int i = 0; i < 4; ++i) {
                int rr = rb + i * 32;
                int rsrc = r0 + rr; if (rsrc >= n) rsrc = n - 1;
                float4 v = *(const float4*)(x + (size_t)rsrc * DIM + kt * KT + q * 4);
                xT[q * 4 + 0][rr] = v.x;
                xT[q * 4 + 1][rr] = v.y;
                xT[q * 4 + 2][rr] = v.z;
                xT[q * 4 + 3][rr] = v.w;
            }
        }
        __syncthreads();

#pragma unroll 4
        for (int k = 0; k < KT; ++k) {
            float a[8], bb[8];
            *(float4*)&a[0]  = *(const float4*)&xT[k][m8];
            *(float4*)&a[4]  = *(const float4*)&xT[k][m8 + 4];
            *(float4*)&bb[0] = *(const float4*)&w1t[k][n8];
            *(float4*)&bb[4] = *(const float4*)&w1t[k][n8 + 4];
#pragma unroll
            for (int i = 0; i < 8; ++i)
#pragma unroll
                for (int j = 0; j < 8; ++j)
                    acc[i][j] = fmaf(a[i], bb[j], acc[i][j]);
        }
        __syncthreads();
    }

    // ---- tanh + layer 2 partial: p_i = sum_j tanh(h_ij + b1_j) * w2_j ----
#pragma unroll
    for (int i = 0; i < 8; ++i) {
        float p = 0.f;
#pragma unroll
        for (int j = 0; j < 8; ++j)
            p += tanhf(acc[i][j] + bv[j]) * wv[j];
        hp[m8 + i][t & 15] = p;
    }
    __syncthreads();

    // ---- reduce 16 col-groups -> score -> e = exp(s) ----
    float eown = 0.f;
    if (t < TILE) {
        float s = 0.f;
#pragma unroll
        for (int c = 0; c < 16; ++c) s += hp[t][c];
        s += b2[0];
        int r = r0 + t;
        eown = (r < n) ? expf(s) : 0.f;
        evals[t] = eown;
    }
    __syncthreads();

    // ---- phase B: weighted per-graph column sums (thread t = column d) ----
    {
        const int d = t;
        float accB = 0.f;
        int gcur = gid[0];
        const int id0 = gcur;
        int slot = 0;
#pragma unroll 4
        for (int r = 0; r < TILE; ++r) {
            int   g = gid[r];                 // wave-uniform
            float e = evals[r];               // broadcast
            int rsrc = r0 + r; if (rsrc >= n) rsrc = n - 1;
            float xv = x[(size_t)rsrc * DIM + d];
            if (g != gcur) {                  // uniform branch; <=1 boundary per 128 rows
                wsp[(size_t)b * 512 + slot * 256 + d] = accB;
                accB = 0.f; slot = 1; gcur = g;
            }
            accB = fmaf(e, xv, accB);
        }
        wsp[(size_t)b * 512 + slot * 256 + d] = accB;
        if (t == 0) wsid[b] = id0;
    }

    // ---- block exp-sum (deterministic shuffle reduce over 128 values) ----
    float rsum = eown;   // 0 for t >= 128
#pragma unroll
    for (int off = 32; off; off >>= 1) rsum += __shfl_down(rsum, off, 64);
    if ((t & 63) == 0) ep[t >> 6] = rsum;
    __syncthreads();
    if (t == 0) wse[b] = ep[0] + ep[1];
}

// ---------------------------------------------------------------------------
// Kernel 2: one block per graph: S = sum(esum) (identical deterministic
// reduction in every block), binary-search graph row range, sum touched
// tile partials, out = acc / S.
// ---------------------------------------------------------------------------
__global__ __launch_bounds__(256) void k_combine(
    const int* __restrict__ batch, const float* __restrict__ wsp,
    const float* __restrict__ wse, const int* __restrict__ wsid,
    float* __restrict__ out, int n, int nblk)
{
    __shared__ float sred[256];
    __shared__ int bounds[2];
    const int g = blockIdx.x;
    const int d = threadIdx.x;

    // global softmax denominator (same order in every block -> bitwise equal)
    float p = 0.f;
    for (int i = d; i < nblk; i += 256) p += wse[i];
    sred[d] = p;
    __syncthreads();
    for (int s = 128; s; s >>= 1) {
        if (d < s) sred[d] += sred[d + s];
        __syncthreads();
    }
    const float S = sred[0];

    if (d < 2) {
        int v = g + d;
        int lo = 0, hi = n;
        while (lo < hi) { int mid = (lo + hi) >> 1; if (batch[mid] < v) lo = mid + 1; else hi = mid; }
        bounds[d] = lo;
    }
    __syncthreads();

    const int st = bounds[0], en = bounds[1];
    float acc = 0.f;
    if (st < en) {
        for (int bb = st >> 7; bb <= (en - 1) >> 7; ++bb) {
            int slot = (wsid[bb] == g) ? 0 : 1;
            acc += wsp[(size_t)bb * 512 + slot * 256 + d];
        }
    }
    out[g * 256 + d] = acc / S;
}

// ---------------------------------------------------------------------------
extern "C" void kernel_launch(void* const* d_in, const int* in_sizes, int n_in,
                              void* d_out, int out_size, void* d_ws, size_t ws_size,
                              hipStream_t stream)
{
    const float* x     = (const float*)d_in[0];
    const int*   batch = (const int*)d_in[1];
    const float* w1    = (const float*)d_in[2];
    const float* b1    = (const float*)d_in[3];
    const float* w2    = (const float*)d_in[4];
    const float* b2    = (const float*)d_in[5];
    float* out = (float*)d_out;

    const int n    = in_sizes[1];                 // 200000
    const int nblk = (n + TILE - 1) / TILE;       // 1563

    float* wsf  = (float*)d_ws;
    float* wsp  = wsf;                                   // nblk*512 floats
    float* wse  = wsf + (size_t)nblk * 512;              // nblk floats
    int*   wsid = (int*)(wsf + (size_t)nblk * 512 + nblk); // nblk ints

    k_scores<<<dim3(nblk), dim3(256), 0, stream>>>(x, batch, w1, b1, w2, b2,
                                                   wsp, wse, wsid, n);
    k_combine<<<dim3(NGRAPHS), dim3(256), 0, stream>>>(batch, wsp, wse, wsid,
                                                       out, n, nblk);
}

// Round 2
// 182.286 us; speedup vs baseline: 1.3094x; 1.3094x over previous
//
#include <hip/hip_runtime.h>

#define NGRAPHS 256
#define DIM     256   // K (input dim)
#define HID     128   // N (hidden dim)
#define TILE    128   // rows per block

typedef __attribute__((ext_vector_type(8))) short bf16x8;
typedef __attribute__((ext_vector_type(4))) float f32x4;

__device__ __forceinline__ ushort f2bf_rne(float f) {
    unsigned u = __float_as_uint(f);
    unsigned r = u + 0x7fffu + ((u >> 16) & 1u);   // round-to-nearest-even
    return (ushort)(r >> 16);
}
__device__ __forceinline__ float bf2f(ushort h) {
    return __uint_as_float(((unsigned)h) << 16);
}
__device__ __forceinline__ float tanh_fast(float x) {
    // tanh(x) = 1 - 2/(1+exp(2x)); v_exp + v_rcp, ~1e-7 abs error
    float e = __expf(2.0f * x);
    return 1.0f - 2.0f * __builtin_amdgcn_rcpf(1.0f + e);
}

// ---------------------------------------------------------------------------
// Prep: w1 [256][128] fp32 -> w1T hi/lo bf16 [128][256] (n-major, k-contig)
// ---------------------------------------------------------------------------
__global__ void k_prep(const float* __restrict__ w1,
                       ushort* __restrict__ w1h, ushort* __restrict__ w1l)
{
    int idx = blockIdx.x * 256 + threadIdx.x;   // 0..32767
    int k  = idx >> 7;
    int nn = idx & 127;
    float v = w1[idx];
    ushort hb = f2bf_rne(v);
    ushort lb = f2bf_rne(v - bf2f(hb));
    w1h[nn * DIM + k] = hb;
    w1l[nn * DIM + k] = lb;
}

// ---------------------------------------------------------------------------
// Main: per 128-row tile: split-bf16 MFMA GEMM -> tanh -> @w2 -> exp ->
// per-graph weighted column partials + block exp-sum. Deterministic.
// ---------------------------------------------------------------------------
__global__ __launch_bounds__(256, 3) void k_scores(
    const float* __restrict__ x, const int* __restrict__ batch,
    const ushort* __restrict__ w1h, const ushort* __restrict__ w1l,
    const float* __restrict__ b1, const float* __restrict__ w2,
    const float* __restrict__ b2,
    float* __restrict__ wsp, float* __restrict__ wse, int* __restrict__ wsid,
    int n)
{
    // A-tile bf16 hi/lo, row stride 40 ushorts (80 B): row*5 mod 8 covers all
    // eight 16B slots of a 128B line -> 2-way max on ds_read_b128 (free).
    __shared__ ushort xh[TILE * 40];
    __shared__ ushort xl[TILE * 40];
    __shared__ float  evals[TILE];
    __shared__ int    gid[TILE];
    __shared__ float  sred[4][2][DIM];   // phase-B cross-wave reduce
    __shared__ float  ep[4];

    const int t    = threadIdx.x;
    const int b    = blockIdx.x;
    const int r0   = b * TILE;
    const int wid  = t >> 6;        // wave 0..3 -> rows wid*32..wid*32+31
    const int lane = t & 63;
    const int lhi  = lane >> 4;     // k-subgroup 0..3
    const int llo  = lane & 15;     // row (A) / col (B) within fragment

    if (t < TILE) {
        int r = r0 + t;
        gid[t] = batch[r < n ? r : (n - 1)];
    }

    f32x4 acc[2][8];
#pragma unroll
    for (int i = 0; i < 2; ++i)
#pragma unroll
        for (int j = 0; j < 8; ++j) acc[i][j] = (f32x4){0.f, 0.f, 0.f, 0.f};

    const int srow = t >> 3;        // 0..31 staging row
    const int scol = (t & 7) * 4;   // k-chunk within 32-wide tile

    for (int ks = 0; ks < 8; ++ks) {
        // ---- stage x[r0..r0+127][ks*32..+32) fp32 -> bf16 hi/lo in LDS ----
        float4 v[4];
#pragma unroll
        for (int i = 0; i < 4; ++i) {
            int rsrc = r0 + srow + i * 32;
            if (rsrc >= n) rsrc = n - 1;
            v[i] = *(const float4*)(x + (size_t)rsrc * DIM + ks * 32 + scol);
        }
#pragma unroll
        for (int i = 0; i < 4; ++i) {
            int row = srow + i * 32;
            float f0 = v[i].x, f1 = v[i].y, f2 = v[i].z, f3 = v[i].w;
            ushort h0 = f2bf_rne(f0), h1 = f2bf_rne(f1),
                   h2 = f2bf_rne(f2), h3 = f2bf_rne(f3);
            ushort l0 = f2bf_rne(f0 - bf2f(h0)), l1 = f2bf_rne(f1 - bf2f(h1)),
                   l2 = f2bf_rne(f2 - bf2f(h2)), l3 = f2bf_rne(f3 - bf2f(h3));
            ushort4 hv; hv.x = h0; hv.y = h1; hv.z = h2; hv.w = h3;
            ushort4 lv; lv.x = l0; lv.y = l1; lv.z = l2; lv.w = l3;
            *(ushort4*)&xh[row * 40 + scol] = hv;
            *(ushort4*)&xl[row * 40 + scol] = lv;
        }
        __syncthreads();

        // ---- fragments + MFMA (A rows: wid*32 + mf*16 + llo) ----
        const int abase = (wid * 32 + llo) * 40 + lhi * 8;
        bf16x8 ah0 = *(const bf16x8*)&xh[abase];
        bf16x8 ah1 = *(const bf16x8*)&xh[abase + 16 * 40];
        bf16x8 al0 = *(const bf16x8*)&xl[abase];
        bf16x8 al1 = *(const bf16x8*)&xl[abase + 16 * 40];

        const size_t boff = (size_t)llo * DIM + ks * 32 + lhi * 8;
#pragma unroll
        for (int nf = 0; nf < 8; ++nf) {
            bf16x8 bh = *(const bf16x8*)(w1h + boff + (size_t)nf * 16 * DIM);
            bf16x8 bl = *(const bf16x8*)(w1l + boff + (size_t)nf * 16 * DIM);
            acc[0][nf] = __builtin_amdgcn_mfma_f32_16x16x32_bf16(ah0, bh, acc[0][nf], 0, 0, 0);
            acc[1][nf] = __builtin_amdgcn_mfma_f32_16x16x32_bf16(ah1, bh, acc[1][nf], 0, 0, 0);
            acc[0][nf] = __builtin_amdgcn_mfma_f32_16x16x32_bf16(ah0, bl, acc[0][nf], 0, 0, 0);
            acc[1][nf] = __builtin_amdgcn_mfma_f32_16x16x32_bf16(ah1, bl, acc[1][nf], 0, 0, 0);
            acc[0][nf] = __builtin_amdgcn_mfma_f32_16x16x32_bf16(al0, bh, acc[0][nf], 0, 0, 0);
            acc[1][nf] = __builtin_amdgcn_mfma_f32_16x16x32_bf16(al1, bh, acc[1][nf], 0, 0, 0);
        }
        __syncthreads();
    }

    // ---- epilogue: tanh + dot(w2) ; C layout: col=llo(+16nf), row=lhi*4+reg ----
    float b2v = b2[0];
    float b1v[8], w2v[8];
#pragma unroll
    for (int nf = 0; nf < 8; ++nf) {
        b1v[nf] = b1[nf * 16 + llo];
        w2v[nf] = w2[nf * 16 + llo];
    }
    float sc[8];
#pragma unroll
    for (int mf = 0; mf < 2; ++mf)
#pragma unroll
        for (int rg = 0; rg < 4; ++rg) {
            float p = 0.f;
#pragma unroll
            for (int nf = 0; nf < 8; ++nf)
                p += tanh_fast(acc[mf][nf][rg] + b1v[nf]) * w2v[nf];
            sc[mf * 4 + rg] = p;
        }
    // reduce over the 16 cols held by llo=0..15
#pragma unroll
    for (int off = 1; off < 16; off <<= 1)
#pragma unroll
        for (int q = 0; q < 8; ++q) sc[q] += __shfl_xor(sc[q], off, 64);

    if (llo == 0) {
#pragma unroll
        for (int mf = 0; mf < 2; ++mf)
#pragma unroll
            for (int rg = 0; rg < 4; ++rg) {
                int row = wid * 32 + mf * 16 + lhi * 4 + rg;
                float s = sc[mf * 4 + rg] + b2v;
                evals[row] = (r0 + row < n) ? __expf(s) : 0.f;
            }
    }
    __syncthreads();

    // ---- phase B: weighted per-graph column partials (wave = 32 rows) ----
    {
        const int g0 = gid[0];
        float4 a0 = {0.f, 0.f, 0.f, 0.f}, a1 = {0.f, 0.f, 0.f, 0.f};
#pragma unroll 4
        for (int rr = 0; rr < 32; ++rr) {
            int row = wid * 32 + rr;
            float e = evals[row];
            int rsrc = r0 + row;
            if (rsrc >= n) rsrc = n - 1;          // e==0 there anyway
            float4 xv = *(const float4*)(x + (size_t)rsrc * DIM + lane * 4);
            if (gid[row] != g0) {                  // wave-uniform branch
                a1.x = fmaf(e, xv.x, a1.x); a1.y = fmaf(e, xv.y, a1.y);
                a1.z = fmaf(e, xv.z, a1.z); a1.w = fmaf(e, xv.w, a1.w);
            } else {
                a0.x = fmaf(e, xv.x, a0.x); a0.y = fmaf(e, xv.y, a0.y);
                a0.z = fmaf(e, xv.z, a0.z); a0.w = fmaf(e, xv.w, a0.w);
            }
        }
        *(float4*)&sred[wid][0][lane * 4] = a0;
        *(float4*)&sred[wid][1][lane * 4] = a1;
    }
    __syncthreads();
    {
        float s0 = sred[0][0][t] + sred[1][0][t] + sred[2][0][t] + sred[3][0][t];
        float s1 = sred[0][1][t] + sred[1][1][t] + sred[2][1][t] + sred[3][1][t];
        wsp[(size_t)b * 512 + t]       = s0;
        wsp[(size_t)b * 512 + 256 + t] = s1;
        if (t == 0) wsid[b] = gid[0];
    }

    // ---- block exp-sum (deterministic) ----
    float rsum = (t < TILE) ? evals[t] : 0.f;
#pragma unroll
    for (int off = 32; off; off >>= 1) rsum += __shfl_down(rsum, off, 64);
    if ((t & 63) == 0) ep[t >> 6] = rsum;
    __syncthreads();
    if (t == 0) wse[b] = ep[0] + ep[1];
}

// ---------------------------------------------------------------------------
// Combine: one block per graph (unchanged from round 1)
// ---------------------------------------------------------------------------
__global__ __launch_bounds__(256) void k_combine(
    const int* __restrict__ batch, const float* __restrict__ wsp,
    const float* __restrict__ wse, const int* __restrict__ wsid,
    float* __restrict__ out, int n, int nblk)
{
    __shared__ float sred[256];
    __shared__ int bounds[2];
    const int g = blockIdx.x;
    const int d = threadIdx.x;

    float p = 0.f;
    for (int i = d; i < nblk; i += 256) p += wse[i];
    sred[d] = p;
    __syncthreads();
    for (int s = 128; s; s >>= 1) {
        if (d < s) sred[d] += sred[d + s];
        __syncthreads();
    }
    const float S = sred[0];

    if (d < 2) {
        int v = g + d;
        int lo = 0, hi = n;
        while (lo < hi) { int mid = (lo + hi) >> 1; if (batch[mid] < v) lo = mid + 1; else hi = mid; }
        bounds[d] = lo;
    }
    __syncthreads();

    const int st = bounds[0], en = bounds[1];
    float acc = 0.f;
    if (st < en) {
        for (int bb = st >> 7; bb <= (en - 1) >> 7; ++bb) {
            int slot = (wsid[bb] == g) ? 0 : 1;
            acc += wsp[(size_t)bb * 512 + slot * 256 + d];
        }
    }
    out[g * 256 + d] = acc / S;
}

// ---------------------------------------------------------------------------
extern "C" void kernel_launch(void* const* d_in, const int* in_sizes, int n_in,
                              void* d_out, int out_size, void* d_ws, size_t ws_size,
                              hipStream_t stream)
{
    const float* x     = (const float*)d_in[0];
    const int*   batch = (const int*)d_in[1];
    const float* w1    = (const float*)d_in[2];
    const float* b1    = (const float*)d_in[3];
    const float* w2    = (const float*)d_in[4];
    const float* b2    = (const float*)d_in[5];
    float* out = (float*)d_out;

    const int n    = in_sizes[1];                 // 200000
    const int nblk = (n + TILE - 1) / TILE;       // 1563

    // ws layout: w1T hi (64KB) | w1T lo (64KB) | wsp | wse | wsid
    ushort* w1h = (ushort*)d_ws;
    ushort* w1l = w1h + DIM * HID;
    float*  wsp = (float*)((char*)d_ws + 2 * DIM * HID * sizeof(ushort));
    float*  wse = wsp + (size_t)nblk * 512;
    int*    wsid = (int*)(wse + nblk);

    k_prep<<<dim3(DIM * HID / 256), dim3(256), 0, stream>>>(w1, w1h, w1l);
    k_scores<<<dim3(nblk), dim3(256), 0, stream>>>(x, batch, w1h, w1l,
                                                   b1, w2, b2, wsp, wse, wsid, n);
    k_combine<<<dim3(NGRAPHS), dim3(256), 0, stream>>>(batch, wsp, wse, wsid,
                                                       out, n, nblk);
}

// Round 3
// 138.612 us; speedup vs baseline: 1.7219x; 1.3151x over previous
//
#include <hip/hip_runtime.h>

#define NGRAPHS 256
#define DIM     256   // K (input dim)
#define HID     128   // N (hidden dim)
#define TILE    128   // rows per block

typedef __attribute__((ext_vector_type(8))) short bf16x8;
typedef __attribute__((ext_vector_type(4))) float f32x4;

__device__ __forceinline__ ushort f2bf_rne(float f) {
    unsigned u = __float_as_uint(f);
    unsigned r = u + 0x7fffu + ((u >> 16) & 1u);
    return (ushort)(r >> 16);
}
__device__ __forceinline__ float bf2f(ushort h) {
    return __uint_as_float(((unsigned)h) << 16);
}
__device__ __forceinline__ float tanh_fast(float x) {
    float e = __expf(2.0f * x);
    return 1.0f - 2.0f * __builtin_amdgcn_rcpf(1.0f + e);
}

// split fp32 -> bf16 hi/lo in registers (hi = truncate, lo = truncate(f-hi);
// combined representation error ~2^-17 relative)
__device__ __forceinline__ void cvt8(float4 v0, float4 v1, bf16x8& h, bf16x8& l) {
    float f[8] = {v0.x, v0.y, v0.z, v0.w, v1.x, v1.y, v1.z, v1.w};
    unsigned hu[8], lu[8];
#pragma unroll
    for (int i = 0; i < 8; ++i) {
        unsigned u = __float_as_uint(f[i]);
        unsigned hb = u & 0xffff0000u;
        hu[i] = u;
        lu[i] = __float_as_uint(f[i] - __uint_as_float(hb));
    }
    union { unsigned w[4]; bf16x8 v; } H, L;
#pragma unroll
    for (int j = 0; j < 4; ++j) {
        H.w[j] = (hu[2 * j] >> 16) | (hu[2 * j + 1] & 0xffff0000u);
        L.w[j] = (lu[2 * j] >> 16) | (lu[2 * j + 1] & 0xffff0000u);
    }
    h = H.v; l = L.v;
}

// ---------------------------------------------------------------------------
// Prep: w1 [256(k)][128(n)] fp32 -> fragment-major bf16 hi/lo:
//   w1f[ks][nf][plane][lane][j], lane = lhi*16+llo, element = w1[ks*32+lhi*8+j][nf*16+llo]
// so a wave's B-fragment load for (ks,nf) is one coalesced 1KB burst.
// ---------------------------------------------------------------------------
__global__ void k_prep(const float* __restrict__ w1, ushort* __restrict__ w1f)
{
    int idx = blockIdx.x * 256 + threadIdx.x;   // 0..32767, k-major
    int k  = idx >> 7, nn = idx & 127;
    int ks = k >> 5, lhi = (k >> 3) & 3, j = k & 7;
    int nf = nn >> 4, llo = nn & 15;
    int lane = lhi * 16 + llo;
    float v = w1[idx];
    ushort hb = f2bf_rne(v);
    ushort lb = f2bf_rne(v - bf2f(hb));
    int base = (ks * 8 + nf) * 1024 + lane * 8 + j;
    w1f[base]       = hb;
    w1f[base + 512] = lb;
}

// ---------------------------------------------------------------------------
// Main: barrier-free split-bf16 MFMA GEMM from registers -> tanh -> @w2 ->
// exp -> per-graph weighted column partials + block exp-sum.
// ---------------------------------------------------------------------------
__global__ __launch_bounds__(256, 3) void k_scores(
    const float* __restrict__ x, const int* __restrict__ batch,
    const ushort* __restrict__ w1f,
    const float* __restrict__ b1, const float* __restrict__ w2,
    const float* __restrict__ b2,
    float* __restrict__ wsp, float* __restrict__ wse, int* __restrict__ wsid,
    int n)
{
    __shared__ float evals[TILE];
    __shared__ int   gid[TILE];
    __shared__ float sred[4][2][DIM];
    __shared__ float ep[4];

    const int t    = threadIdx.x;
    const int b    = blockIdx.x;
    const int r0   = b * TILE;
    const int wid  = t >> 6;
    const int lane = t & 63;
    const int lhi  = lane >> 4;
    const int llo  = lane & 15;

    if (t < TILE) {
        int r = r0 + t;
        gid[t] = batch[r < n ? r : (n - 1)];
    }

    // this lane's two A-fragment rows (mf=0,1)
    int row0 = r0 + wid * 32 + llo;
    int row1 = row0 + 16;
    if (row0 >= n) row0 = n - 1;
    if (row1 >= n) row1 = n - 1;
    const float*  xr0   = x + (size_t)row0 * DIM + lhi * 8;
    const float*  xr1   = x + (size_t)row1 * DIM + lhi * 8;
    const ushort* bbase = w1f + lane * 8;

    f32x4 acc[2][8];
#pragma unroll
    for (int i = 0; i < 2; ++i)
#pragma unroll
        for (int j = 0; j < 8; ++j) acc[i][j] = (f32x4){0.f, 0.f, 0.f, 0.f};

#pragma unroll
    for (int ks = 0; ks < 8; ++ks) {
        float4 a0 = *(const float4*)(xr0 + ks * 32);
        float4 a1 = *(const float4*)(xr0 + ks * 32 + 4);
        float4 c0 = *(const float4*)(xr1 + ks * 32);
        float4 c1 = *(const float4*)(xr1 + ks * 32 + 4);
        bf16x8 ah0, al0, ah1, al1;
        cvt8(a0, a1, ah0, al0);
        cvt8(c0, c1, ah1, al1);
#pragma unroll
        for (int nf = 0; nf < 8; ++nf) {
            const ushort* bp = bbase + ks * 8192 + nf * 1024;
            bf16x8 bh = *(const bf16x8*)bp;
            bf16x8 bl = *(const bf16x8*)(bp + 512);
            acc[0][nf] = __builtin_amdgcn_mfma_f32_16x16x32_bf16(ah0, bh, acc[0][nf], 0, 0, 0);
            acc[1][nf] = __builtin_amdgcn_mfma_f32_16x16x32_bf16(ah1, bh, acc[1][nf], 0, 0, 0);
            acc[0][nf] = __builtin_amdgcn_mfma_f32_16x16x32_bf16(ah0, bl, acc[0][nf], 0, 0, 0);
            acc[1][nf] = __builtin_amdgcn_mfma_f32_16x16x32_bf16(ah1, bl, acc[1][nf], 0, 0, 0);
            acc[0][nf] = __builtin_amdgcn_mfma_f32_16x16x32_bf16(al0, bh, acc[0][nf], 0, 0, 0);
            acc[1][nf] = __builtin_amdgcn_mfma_f32_16x16x32_bf16(al1, bh, acc[1][nf], 0, 0, 0);
        }
    }

    // ---- epilogue: tanh + dot(w2); C layout: col=llo+16nf, row=lhi*4+rg ----
    float b2v = b2[0];
    float b1v[8], w2v[8];
#pragma unroll
    for (int nf = 0; nf < 8; ++nf) {
        b1v[nf] = b1[nf * 16 + llo];
        w2v[nf] = w2[nf * 16 + llo];
    }
    float sc[8];
#pragma unroll
    for (int mf = 0; mf < 2; ++mf)
#pragma unroll
        for (int rg = 0; rg < 4; ++rg) {
            float p = 0.f;
#pragma unroll
            for (int nf = 0; nf < 8; ++nf)
                p += tanh_fast(acc[mf][nf][rg] + b1v[nf]) * w2v[nf];
            sc[mf * 4 + rg] = p;
        }
#pragma unroll
    for (int off = 1; off < 16; off <<= 1)
#pragma unroll
        for (int q = 0; q < 8; ++q) sc[q] += __shfl_xor(sc[q], off, 64);

    if (llo == 0) {
#pragma unroll
        for (int mf = 0; mf < 2; ++mf)
#pragma unroll
            for (int rg = 0; rg < 4; ++rg) {
                int row = wid * 32 + mf * 16 + lhi * 4 + rg;
                float s = sc[mf * 4 + rg] + b2v;
                evals[row] = (r0 + row < n) ? __expf(s) : 0.f;
            }
    }
    __syncthreads();   // evals + gid visible block-wide

    // ---- phase B: weighted per-graph column partials (wave = 32 rows) ----
    {
        const int g0 = gid[0];
        float4 a0 = {0.f, 0.f, 0.f, 0.f}, a1 = {0.f, 0.f, 0.f, 0.f};
#pragma unroll 4
        for (int rr = 0; rr < 32; ++rr) {
            int row = wid * 32 + rr;
            float e = evals[row];
            int rsrc = r0 + row;
            if (rsrc >= n) rsrc = n - 1;          // e==0 there anyway
            float4 xv = *(const float4*)(x + (size_t)rsrc * DIM + lane * 4);
            if (gid[row] != g0) {
                a1.x = fmaf(e, xv.x, a1.x); a1.y = fmaf(e, xv.y, a1.y);
                a1.z = fmaf(e, xv.z, a1.z); a1.w = fmaf(e, xv.w, a1.w);
            } else {
                a0.x = fmaf(e, xv.x, a0.x); a0.y = fmaf(e, xv.y, a0.y);
                a0.z = fmaf(e, xv.z, a0.z); a0.w = fmaf(e, xv.w, a0.w);
            }
        }
        *(float4*)&sred[wid][0][lane * 4] = a0;
        *(float4*)&sred[wid][1][lane * 4] = a1;
    }
    __syncthreads();
    {
        float s0 = sred[0][0][t] + sred[1][0][t] + sred[2][0][t] + sred[3][0][t];
        float s1 = sred[0][1][t] + sred[1][1][t] + sred[2][1][t] + sred[3][1][t];
        wsp[(size_t)b * 512 + t]       = s0;
        wsp[(size_t)b * 512 + 256 + t] = s1;
        if (t == 0) wsid[b] = gid[0];
    }

    // ---- block exp-sum (deterministic) ----
    float rsum = (t < TILE) ? evals[t] : 0.f;
#pragma unroll
    for (int off = 32; off; off >>= 1) rsum += __shfl_down(rsum, off, 64);
    if ((t & 63) == 0) ep[t >> 6] = rsum;
    __syncthreads();
    if (t == 0) wse[b] = ep[0] + ep[1];
}

// ---------------------------------------------------------------------------
// Combine: one block per graph
// ---------------------------------------------------------------------------
__global__ __launch_bounds__(256) void k_combine(
    const int* __restrict__ batch, const float* __restrict__ wsp,
    const float* __restrict__ wse, const int* __restrict__ wsid,
    float* __restrict__ out, int n, int nblk)
{
    __shared__ float sred[256];
    __shared__ int bounds[2];
    const int g = blockIdx.x;
    const int d = threadIdx.x;

    float p = 0.f;
    for (int i = d; i < nblk; i += 256) p += wse[i];
    sred[d] = p;
    __syncthreads();
    for (int s = 128; s; s >>= 1) {
        if (d < s) sred[d] += sred[d + s];
        __syncthreads();
    }
    const float S = sred[0];

    if (d < 2) {
        int v = g + d;
        int lo = 0, hi = n;
        while (lo < hi) { int mid = (lo + hi) >> 1; if (batch[mid] < v) lo = mid + 1; else hi = mid; }
        bounds[d] = lo;
    }
    __syncthreads();

    const int st = bounds[0], en = bounds[1];
    float acc = 0.f;
    if (st < en) {
        for (int bb = st >> 7; bb <= (en - 1) >> 7; ++bb) {
            int slot = (wsid[bb] == g) ? 0 : 1;
            acc += wsp[(size_t)bb * 512 + slot * 256 + d];
        }
    }
    out[g * 256 + d] = acc / S;
}

// ---------------------------------------------------------------------------
extern "C" void kernel_launch(void* const* d_in, const int* in_sizes, int n_in,
                              void* d_out, int out_size, void* d_ws, size_t ws_size,
                              hipStream_t stream)
{
    const float* x     = (const float*)d_in[0];
    const int*   batch = (const int*)d_in[1];
    const float* w1    = (const float*)d_in[2];
    const float* b1    = (const float*)d_in[3];
    const float* w2    = (const float*)d_in[4];
    const float* b2    = (const float*)d_in[5];
    float* out = (float*)d_out;

    const int n    = in_sizes[1];                 // 200000
    const int nblk = (n + TILE - 1) / TILE;       // 1563

    // ws layout: w1f fragment-major hi/lo (128KB) | wsp | wse | wsid
    ushort* w1f = (ushort*)d_ws;
    float*  wsp = (float*)((char*)d_ws + (size_t)DIM * HID * 2 * sizeof(ushort));
    float*  wse = wsp + (size_t)nblk * 512;
    int*    wsid = (int*)(wse + nblk);

    k_prep<<<dim3(DIM * HID / 256), dim3(256), 0, stream>>>(w1, w1f);
    k_scores<<<dim3(nblk), dim3(256), 0, stream>>>(x, batch, w1f,
                                                   b1, w2, b2, wsp, wse, wsid, n);
    k_combine<<<dim3(NGRAPHS), dim3(256), 0, stream>>>(batch, wsp, wse, wsid,
                                                       out, n, nblk);
}

// Round 4
// 94.776 us; speedup vs baseline: 2.5183x; 1.4625x over previous
//
#include <hip/hip_runtime.h>

#define NGRAPHS 256
#define DIM     256   // K (input dim)
#define HID     128   // N (hidden dim)
#define TILE    128   // rows per block

typedef __attribute__((ext_vector_type(8))) short bf16x8;
typedef __attribute__((ext_vector_type(4))) float f32x4;

__device__ __forceinline__ ushort f2bf_rne(float f) {
    unsigned u = __float_as_uint(f);
    unsigned r = u + 0x7fffu + ((u >> 16) & 1u);
    return (ushort)(r >> 16);
}
__device__ __forceinline__ float bf2f(ushort h) {
    return __uint_as_float(((unsigned)h) << 16);
}
__device__ __forceinline__ float tanh_fast(float x) {
    float e = __expf(2.0f * x);
    return 1.0f - 2.0f * __builtin_amdgcn_rcpf(1.0f + e);
}

// fire-and-forget global->LDS DMA, 16B per lane; lds ptr must be wave-uniform
__device__ __forceinline__ void glds16(const void* g, void* l) {
    __builtin_amdgcn_global_load_lds(
        (const __attribute__((address_space(1))) unsigned int*)g,
        (__attribute__((address_space(3))) unsigned int*)l, 16, 0, 0);
}

// split fp32 -> bf16 hi/lo in registers (hi = truncate, lo = truncate(f-hi))
__device__ __forceinline__ void cvt8(float4 v0, float4 v1, bf16x8& h, bf16x8& l) {
    float f[8] = {v0.x, v0.y, v0.z, v0.w, v1.x, v1.y, v1.z, v1.w};
    unsigned hu[8], lu[8];
#pragma unroll
    for (int i = 0; i < 8; ++i) {
        unsigned u = __float_as_uint(f[i]);
        unsigned hb = u & 0xffff0000u;
        hu[i] = u;
        lu[i] = __float_as_uint(f[i] - __uint_as_float(hb));
    }
    union { unsigned w[4]; bf16x8 v; } H, L;
#pragma unroll
    for (int j = 0; j < 4; ++j) {
        H.w[j] = (hu[2 * j] >> 16) | (hu[2 * j + 1] & 0xffff0000u);
        L.w[j] = (lu[2 * j] >> 16) | (lu[2 * j + 1] & 0xffff0000u);
    }
    h = H.v; l = L.v;
}

// ---------------------------------------------------------------------------
// Prep: w1 [256(k)][128(n)] fp32 -> fragment-major bf16 hi/lo:
//   w1f[(ks*8+nf)*1024 + plane*512 + lane*8 + j],
//   lane = lhi*16+llo, element = w1[ks*32+lhi*8+j][nf*16+llo]
// ---------------------------------------------------------------------------
__global__ void k_prep(const float* __restrict__ w1, ushort* __restrict__ w1f)
{
    int idx = blockIdx.x * 256 + threadIdx.x;   // 0..32767, k-major
    int k  = idx >> 7, nn = idx & 127;
    int ks = k >> 5, lhi = (k >> 3) & 3, j = k & 7;
    int nf = nn >> 4, llo = nn & 15;
    int lane = lhi * 16 + llo;
    float v = w1[idx];
    ushort hb = f2bf_rne(v);
    ushort lb = f2bf_rne(v - bf2f(hb));
    int base = (ks * 8 + nf) * 1024 + lane * 8 + j;
    w1f[base]       = hb;
    w1f[base + 512] = lb;
}

// ---------------------------------------------------------------------------
// Main: LDS-staged (global_load_lds) split-bf16 MFMA GEMM -> tanh -> @w2 ->
// exp -> per-graph weighted column partials + block exp-sum. Deterministic.
// ---------------------------------------------------------------------------
__global__ __launch_bounds__(256, 3) void k_scores(
    const float* __restrict__ x, const int* __restrict__ batch,
    const ushort* __restrict__ w1f,
    const float* __restrict__ b1, const float* __restrict__ w2,
    const float* __restrict__ b2,
    float* __restrict__ wsp, float* __restrict__ wse, int* __restrict__ wsid,
    int n)
{
    // xs: 128 rows x 32 floats, 16B-chunk XOR-swizzled: chunk slot s of row r
    // holds global chunk q = s ^ (r&7). Written linearly by glds16 with
    // pre-swizzled SOURCE addresses (swizzle on both sides or neither).
    __shared__ float  xs[TILE * 32];      // 16 KB
    __shared__ ushort bs[8 * 1024];       // 16 KB, [nf][plane][lane][8] for cur ks
    __shared__ float  evals[TILE];
    __shared__ int    gid[TILE];
    __shared__ float  sred[4][2][DIM];    // 8 KB
    __shared__ float  ep[4];

    const int t    = threadIdx.x;
    const int b    = blockIdx.x;
    const int r0   = b * TILE;
    const int wid  = t >> 6;
    const int lane = t & 63;
    const int lhi  = lane >> 4;
    const int llo  = lane & 15;

    if (t < TILE) {
        int r = r0 + t;
        gid[t] = batch[r < n ? r : (n - 1)];
    }

    f32x4 acc[2][8];
#pragma unroll
    for (int i = 0; i < 2; ++i)
#pragma unroll
        for (int j = 0; j < 8; ++j) acc[i][j] = (f32x4){0.f, 0.f, 0.f, 0.f};

    // A-fragment LDS chunk addresses (block-relative rows ra0, ra0+16)
    const int ra0 = wid * 32 + llo;
    const int ra1 = ra0 + 16;               // (ra1 & 7) == (ra0 & 7)
    const int rb7 = ra0 & 7;
    const int c00 = (ra0 * 8 + ((2 * lhi)     ^ rb7)) * 4;
    const int c01 = (ra0 * 8 + ((2 * lhi + 1) ^ rb7)) * 4;
    const int c10 = (ra1 * 8 + ((2 * lhi)     ^ rb7)) * 4;
    const int c11 = (ra1 * 8 + ((2 * lhi + 1) ^ rb7)) * 4;

    for (int ks = 0; ks < 8; ++ks) {
        // ---- stage: x slice (swizzled source) + B fragment tile (linear) ----
#pragma unroll
        for (int i = 0; i < 4; ++i) {
            int p = i * 256 + t;            // 16B-chunk index 0..1023
            int r = p >> 3, s = p & 7;
            int q = s ^ (r & 7);
            int rsrc = r0 + r; if (rsrc >= n) rsrc = n - 1;
            glds16(x + (size_t)rsrc * DIM + ks * 32 + q * 4,
                   &xs[(i * 256 + wid * 64) * 4]);
            glds16(w1f + (size_t)ks * 8192 + (size_t)p * 8,
                   &bs[(i * 256 + wid * 64) * 8]);
        }
        __syncthreads();

        // ---- A fragments from LDS + cvt ----
        float4 a0 = *(const float4*)&xs[c00];
        float4 a1 = *(const float4*)&xs[c01];
        float4 c0 = *(const float4*)&xs[c10];
        float4 c1 = *(const float4*)&xs[c11];
        bf16x8 ah0, al0, ah1, al1;
        cvt8(a0, a1, ah0, al0);
        cvt8(c0, c1, ah1, al1);

#pragma unroll
        for (int nf = 0; nf < 8; ++nf) {
            bf16x8 bh = *(const bf16x8*)&bs[(nf * 2 + 0) * 512 + lane * 8];
            bf16x8 bl = *(const bf16x8*)&bs[(nf * 2 + 1) * 512 + lane * 8];
            acc[0][nf] = __builtin_amdgcn_mfma_f32_16x16x32_bf16(ah0, bh, acc[0][nf], 0, 0, 0);
            acc[1][nf] = __builtin_amdgcn_mfma_f32_16x16x32_bf16(ah1, bh, acc[1][nf], 0, 0, 0);
            acc[0][nf] = __builtin_amdgcn_mfma_f32_16x16x32_bf16(ah0, bl, acc[0][nf], 0, 0, 0);
            acc[1][nf] = __builtin_amdgcn_mfma_f32_16x16x32_bf16(ah1, bl, acc[1][nf], 0, 0, 0);
            acc[0][nf] = __builtin_amdgcn_mfma_f32_16x16x32_bf16(al0, bh, acc[0][nf], 0, 0, 0);
            acc[1][nf] = __builtin_amdgcn_mfma_f32_16x16x32_bf16(al1, bh, acc[1][nf], 0, 0, 0);
        }
        __syncthreads();
    }

    // ---- epilogue: tanh + dot(w2); C layout: col=llo+16nf, row=lhi*4+rg ----
    float b2v = b2[0];
    float b1v[8], w2v[8];
#pragma unroll
    for (int nf = 0; nf < 8; ++nf) {
        b1v[nf] = b1[nf * 16 + llo];
        w2v[nf] = w2[nf * 16 + llo];
    }
    float sc[8];
#pragma unroll
    for (int mf = 0; mf < 2; ++mf)
#pragma unroll
        for (int rg = 0; rg < 4; ++rg) {
            float p = 0.f;
#pragma unroll
            for (int nf = 0; nf < 8; ++nf)
                p += tanh_fast(acc[mf][nf][rg] + b1v[nf]) * w2v[nf];
            sc[mf * 4 + rg] = p;
        }
#pragma unroll
    for (int off = 1; off < 16; off <<= 1)
#pragma unroll
        for (int q = 0; q < 8; ++q) sc[q] += __shfl_xor(sc[q], off, 64);

    if (llo == 0) {
#pragma unroll
        for (int mf = 0; mf < 2; ++mf)
#pragma unroll
            for (int rg = 0; rg < 4; ++rg) {
                int row = wid * 32 + mf * 16 + lhi * 4 + rg;
                float s = sc[mf * 4 + rg] + b2v;
                evals[row] = (r0 + row < n) ? __expf(s) : 0.f;
            }
    }
    __syncthreads();   // evals + gid visible block-wide

    // ---- phase B: weighted per-graph column partials, 8-deep load batches ----
    {
        const int g0 = gid[0];
        float4 a0 = {0.f, 0.f, 0.f, 0.f}, a1 = {0.f, 0.f, 0.f, 0.f};
        for (int bt = 0; bt < 4; ++bt) {
            float4 xv[8];
#pragma unroll
            for (int j = 0; j < 8; ++j) {
                int rsrc = r0 + wid * 32 + bt * 8 + j;
                if (rsrc >= n) rsrc = n - 1;          // e==0 there anyway
                xv[j] = *(const float4*)(x + (size_t)rsrc * DIM + lane * 4);
            }
#pragma unroll
            for (int j = 0; j < 8; ++j) {
                int row = wid * 32 + bt * 8 + j;
                float e = evals[row];
                if (gid[row] != g0) {
                    a1.x = fmaf(e, xv[j].x, a1.x); a1.y = fmaf(e, xv[j].y, a1.y);
                    a1.z = fmaf(e, xv[j].z, a1.z); a1.w = fmaf(e, xv[j].w, a1.w);
                } else {
                    a0.x = fmaf(e, xv[j].x, a0.x); a0.y = fmaf(e, xv[j].y, a0.y);
                    a0.z = fmaf(e, xv[j].z, a0.z); a0.w = fmaf(e, xv[j].w, a0.w);
                }
            }
        }
        *(float4*)&sred[wid][0][lane * 4] = a0;
        *(float4*)&sred[wid][1][lane * 4] = a1;
    }
    __syncthreads();
    {
        float s0 = sred[0][0][t] + sred[1][0][t] + sred[2][0][t] + sred[3][0][t];
        float s1 = sred[0][1][t] + sred[1][1][t] + sred[2][1][t] + sred[3][1][t];
        wsp[(size_t)b * 512 + t]       = s0;
        wsp[(size_t)b * 512 + 256 + t] = s1;
        if (t == 0) wsid[b] = gid[0];
    }

    // ---- block exp-sum (deterministic) ----
    float rsum = (t < TILE) ? evals[t] : 0.f;
#pragma unroll
    for (int off = 32; off; off >>= 1) rsum += __shfl_down(rsum, off, 64);
    if ((t & 63) == 0) ep[t >> 6] = rsum;
    __syncthreads();
    if (t == 0) wse[b] = ep[0] + ep[1];
}

// ---------------------------------------------------------------------------
// Combine: one block per graph
// ---------------------------------------------------------------------------
__global__ __launch_bounds__(256) void k_combine(
    const int* __restrict__ batch, const float* __restrict__ wsp,
    const float* __restrict__ wse, const int* __restrict__ wsid,
    float* __restrict__ out, int n, int nblk)
{
    __shared__ float sred[256];
    __shared__ int bounds[2];
    const int g = blockIdx.x;
    const int d = threadIdx.x;

    float p = 0.f;
    for (int i = d; i < nblk; i += 256) p += wse[i];
    sred[d] = p;
    __syncthreads();
    for (int s = 128; s; s >>= 1) {
        if (d < s) sred[d] += sred[d + s];
        __syncthreads();
    }
    const float S = sred[0];

    if (d < 2) {
        int v = g + d;
        int lo = 0, hi = n;
        while (lo < hi) { int mid = (lo + hi) >> 1; if (batch[mid] < v) lo = mid + 1; else hi = mid; }
        bounds[d] = lo;
    }
    __syncthreads();

    const int st = bounds[0], en = bounds[1];
    float acc = 0.f;
    if (st < en) {
        for (int bb = st >> 7; bb <= (en - 1) >> 7; ++bb) {
            int slot = (wsid[bb] == g) ? 0 : 1;
            acc += wsp[(size_t)bb * 512 + slot * 256 + d];
        }
    }
    out[g * 256 + d] = acc / S;
}

// ---------------------------------------------------------------------------
extern "C" void kernel_launch(void* const* d_in, const int* in_sizes, int n_in,
                              void* d_out, int out_size, void* d_ws, size_t ws_size,
                              hipStream_t stream)
{
    const float* x     = (const float*)d_in[0];
    const int*   batch = (const int*)d_in[1];
    const float* w1    = (const float*)d_in[2];
    const float* b1    = (const float*)d_in[3];
    const float* w2    = (const float*)d_in[4];
    const float* b2    = (const float*)d_in[5];
    float* out = (float*)d_out;

    const int n    = in_sizes[1];                 // 200000
    const int nblk = (n + TILE - 1) / TILE;       // 1563

    // ws layout: w1f fragment-major hi/lo (128KB) | wsp | wse | wsid
    ushort* w1f = (ushort*)d_ws;
    float*  wsp = (float*)((char*)d_ws + (size_t)DIM * HID * 2 * sizeof(ushort));
    float*  wse = wsp + (size_t)nblk * 512;
    int*    wsid = (int*)(wse + nblk);

    k_prep<<<dim3(DIM * HID / 256), dim3(256), 0, stream>>>(w1, w1f);
    k_scores<<<dim3(nblk), dim3(256), 0, stream>>>(x, batch, w1f,
                                                   b1, w2, b2, wsp, wse, wsid, n);
    k_combine<<<dim3(NGRAPHS), dim3(256), 0, stream>>>(batch, wsp, wse, wsid,
                                                       out, n, nblk);
}